// Round 5
// baseline (192.072 us; speedup 1.0000x reference)
//
#include <hip/hip_runtime.h>
#include <math.h>

#define NH 16
#define QL 2048
#define SL 2048
#define DD 64
#define PSTR 72
#define QK_SCALE_LOG2E 0.1803368801111f   // (8/64) * log2(e): fold softmax scale + ln2 into Q

typedef __attribute__((ext_vector_type(8))) short short8;
typedef __attribute__((ext_vector_type(4))) float floatx4;
typedef __attribute__((ext_vector_type(4))) unsigned short ushort4v;
typedef __attribute__((ext_vector_type(8))) unsigned short ushort8v;

__device__ __forceinline__ unsigned short f2bf(float x) {   // RNE fp32->bf16
    unsigned u = __float_as_uint(x);
    u += 0x7FFFu + ((u >> 16) & 1u);
    return (unsigned short)(u >> 16);
}

// ---------------- prep: y=0 Q*(scale*log2e)->bf16, y=1 K->bf16, y=2 V->V^T bf16 ----------------
__global__ __launch_bounds__(256) void prep(
    const float* __restrict__ Qf, const float* __restrict__ Kf, const float* __restrict__ Vf,
    unsigned short* __restrict__ Qb, unsigned short* __restrict__ Kb, unsigned short* __restrict__ Vtb)
{
    if (blockIdx.y < 2) {
        int idx = blockIdx.x * 256 + threadIdx.x;          // float4 index, NH*QL*DD/4 = 524288
        const float4* src; unsigned short* dst; float scale;
        if (blockIdx.y == 0) { src = (const float4*)Qf; dst = Qb; scale = QK_SCALE_LOG2E; }
        else                 { src = (const float4*)Kf; dst = Kb; scale = 1.0f; }
        float4 v = src[idx];
        ushort4v h = { f2bf(v.x * scale), f2bf(v.y * scale), f2bf(v.z * scale), f2bf(v.w * scale) };
        *(ushort4v*)(dst + (size_t)idx * 4) = h;
    } else {
        if (blockIdx.x >= 512) return;                     // 16 heads x 32 s-tiles
        __shared__ unsigned short sT[64][PSTR];
        int bx = blockIdx.x;
        int n = bx >> 5, stile = bx & 31, s0 = stile * 64;
        int tid = (int)threadIdx.x;
        const float* vb = Vf + ((size_t)n * SL + s0) * DD;
        #pragma unroll
        for (int i = 0; i < 4; ++i) {
            int idx = tid + i * 256;
            int r = idx >> 4, c = (idx & 15) << 2;
            float4 v = *(const float4*)(vb + r * DD + c);
            sT[c + 0][r] = f2bf(v.x);
            sT[c + 1][r] = f2bf(v.y);
            sT[c + 2][r] = f2bf(v.z);
            sT[c + 3][r] = f2bf(v.w);
        }
        __syncthreads();
        int d = tid >> 2, sg = tid & 3;
        unsigned short* out = Vtb + (size_t)n * DD * SL + (size_t)d * SL + s0 + sg * 16;
        ushort8v a, b;
        #pragma unroll
        for (int i = 0; i < 8; ++i) { a[i] = sT[d][sg * 16 + i]; b[i] = sT[d][sg * 16 + 8 + i]; }
        *(ushort8v*)(out) = a;
        *(ushort8v*)(out + 8) = b;
    }
}

// ---------------- attention: barrier-free K-loop, register-direct K/V fragments ----------------
__global__ __launch_bounds__(256, 3) void attn_mfma_reg(
    const unsigned short* __restrict__ Qb, const unsigned short* __restrict__ Kb,
    const unsigned short* __restrict__ Vtb, const int* __restrict__ plen_g,
    float* __restrict__ Op, float* __restrict__ Lp, int spl)
{
    __shared__ unsigned short sP[4 * 16 * PSTR];   // per-wave P[q][s], wave-private (lgkmcnt-ordered)

    const int blk = blockIdx.x;
    const int n  = blk & (NH - 1);
    const int qt = blk >> 4;
    const int q0 = qt * 64;
    const int sp = blockIdx.y;
    const int sbeg = sp * spl;
    const int plen = plen_g[n];
    const int ntile = spl >> 6;
    const bool hasdiag = (q0 >= sbeg) && (q0 < sbeg + spl);
    if (!((sbeg < plen) || hasdiag)) return;       // must match combine's predicate

    const int tid  = (int)threadIdx.x;
    const int wave = tid >> 6, lane = tid & 63, quad = lane >> 4, l16 = lane & 15;

    // active tiles: [0, base) prefix tiles + the diagonal tile if beyond base
    int rem  = plen - sbeg;
    int base = (rem > 0) ? min((rem + 63) >> 6, ntile) : 0;
    int td   = hasdiag ? ((q0 - sbeg) >> 6) : -1;
    int total = base + ((td >= base) ? 1 : 0);

    const int qrow  = wave * 16 + l16;             // local q row within block
    const int qglob = q0 + qrow;

    // Q fragments register-direct from global (loop-invariant): B[n=q][k=ks*32+quad*8+j]
    const unsigned short* qg = Qb + ((size_t)(n * QL + qglob)) * DD + quad * 8;
    short8 bQ0 = *(const short8*)(qg);
    short8 bQ1 = *(const short8*)(qg + 32);

    const unsigned short* kh = Kb  + (size_t)n * SL * DD;
    const unsigned short* vh = Vtb + (size_t)n * DD * SL;

    floatx4 acc[4];
    #pragma unroll
    for (int dt = 0; dt < 4; ++dt) acc[dt] = (floatx4){0.f, 0.f, 0.f, 0.f};
    float lsum = 0.f;
    unsigned short* pw = sP + qrow * PSTR;

    for (int i = 0; i < total; ++i) {
        const int t  = (i < base) ? i : td;
        const int s0 = sbeg + t * 64;

        // ---- K fragments: A[m=s][k], lane row = s0+st2*16+l16, 16B contiguous, coalesced ----
        const unsigned short* kt = kh + ((size_t)(s0 + l16)) * DD + quad * 8;
        short8 aK[4][2];
        #pragma unroll
        for (int st2 = 0; st2 < 4; ++st2) {
            aK[st2][0] = *(const short8*)(kt + (size_t)st2 * 16 * DD);
            aK[st2][1] = *(const short8*)(kt + (size_t)st2 * 16 * DD + 32);
        }
        // ---- V^T fragments (issued early; consumed after softmax): B[n=d][k=s] ----
        const unsigned short* vt = vh + (size_t)l16 * SL + s0 + quad * 8;
        short8 bV[4][2];
        #pragma unroll
        for (int dt = 0; dt < 4; ++dt) {
            bV[dt][0] = *(const short8*)(vt + (size_t)dt * 16 * SL);
            bV[dt][1] = *(const short8*)(vt + (size_t)dt * 16 * SL + 32);
        }

        // ---- S^T = K·Q^T : D[s=st2*16+quad*4+r][q=l16] ----
        floatx4 sf[4];
        #pragma unroll
        for (int st2 = 0; st2 < 4; ++st2) {
            sf[st2] = (floatx4){0.f, 0.f, 0.f, 0.f};
            sf[st2] = __builtin_amdgcn_mfma_f32_16x16x32_bf16(aK[st2][0], bQ0, sf[st2], 0, 0, 0);
            sf[st2] = __builtin_amdgcn_mfma_f32_16x16x32_bf16(aK[st2][1], bQ1, sf[st2], 0, 0, 0);
        }

        // ---- fixed-max softmax: p = exp2(prescaled score); no cross-lane ops ----
        if (s0 + 64 <= plen) {                     // fully-valid tile
            #pragma unroll
            for (int st2 = 0; st2 < 4; ++st2) {
                float p0 = __builtin_amdgcn_exp2f(sf[st2][0]);
                float p1 = __builtin_amdgcn_exp2f(sf[st2][1]);
                float p2 = __builtin_amdgcn_exp2f(sf[st2][2]);
                float p3 = __builtin_amdgcn_exp2f(sf[st2][3]);
                lsum += (p0 + p1) + (p2 + p3);
                ushort4v pk = { f2bf(p0), f2bf(p1), f2bf(p2), f2bf(p3) };
                *(ushort4v*)(pw + st2 * 16 + quad * 4) = pk;   // P^T-pack: r contiguous in s
            }
        } else {
            #pragma unroll
            for (int st2 = 0; st2 < 4; ++st2) {
                float p[4];
                #pragma unroll
                for (int r = 0; r < 4; ++r) {
                    int s = s0 + st2 * 16 + quad * 4 + r;
                    bool valid = (s < plen) || (s == qglob);
                    p[r] = __builtin_amdgcn_exp2f(valid ? sf[st2][r] : -INFINITY);
                    lsum += p[r];
                }
                ushort4v pk = { f2bf(p[0]), f2bf(p[1]), f2bf(p[2]), f2bf(p[3]) };
                *(ushort4v*)(pw + st2 * 16 + quad * 4) = pk;
            }
        }

        // ---- PV: O[q][d] += P·V (A = P rows q from LDS, B = V^T frags in regs) ----
        #pragma unroll
        for (int ks = 0; ks < 2; ++ks) {
            short8 aP = *(const short8*)(sP + qrow * PSTR + ks * 32 + quad * 8);
            #pragma unroll
            for (int dt = 0; dt < 4; ++dt)
                acc[dt] = __builtin_amdgcn_mfma_f32_16x16x32_bf16(aP, bV[dt][ks], acc[dt], 0, 0, 0);
        }
    }

    // ---- epilogue: unnormalized partials ----
    lsum += __shfl_xor(lsum, 16, 64);
    lsum += __shfl_xor(lsum, 32, 64);
    if (quad == 0)
        Lp[((size_t)sp * NH + n) * QL + q0 + qrow] = lsum;

    float* ob = Op + (((size_t)sp * NH + n) * QL + q0) * DD;
    #pragma unroll
    for (int r = 0; r < 4; ++r) {
        int ql = wave * 16 + quad * 4 + r;
        #pragma unroll
        for (int dt = 0; dt < 4; ++dt)
            ob[(size_t)ql * DD + dt * 16 + l16] = acc[dt][r];
    }
}

// ---------------- combine: O = sum(Op) / sum(Lp) over contributing splits ----------------
__global__ __launch_bounds__(256) void combine(
    const float* __restrict__ Op, const float* __restrict__ Lp,
    const int* __restrict__ plen_g, float* __restrict__ Og, int nsplit, int spl)
{
    int idx = blockIdx.x * 256 + (int)threadIdx.x;    // float4 index, NH*QL*DD/4
    int d4 = idx & 15;
    int q  = (idx >> 4) & (QL - 1);
    int n  = idx >> 15;
    int plen = plen_g[n];
    int spd = q / spl;
    float4 s = {0.f, 0.f, 0.f, 0.f};
    float l = 0.f;
    for (int sp = 0; sp < nsplit; ++sp) {
        if ((sp * spl < plen) || (sp == spd)) {       // same predicate as attn early-exit
            const float* ob = Op + (((size_t)sp * NH + n) * QL + q) * DD;
            float4 v = *(const float4*)(ob + d4 * 4);
            s.x += v.x; s.y += v.y; s.z += v.z; s.w += v.w;
            l += Lp[((size_t)sp * NH + n) * QL + q];
        }
    }
    float inv = 1.0f / l;
    float4 o = { s.x * inv, s.y * inv, s.z * inv, s.w * inv };
    *(float4*)(Og + ((size_t)n * QL + q) * DD + d4 * 4) = o;
}

extern "C" void kernel_launch(void* const* d_in, const int* in_sizes, int n_in,
                              void* d_out, int out_size, void* d_ws, size_t ws_size,
                              hipStream_t stream) {
    const float* Qf   = (const float*)d_in[0];
    const float* Kf   = (const float*)d_in[1];
    const float* Vf   = (const float*)d_in[2];
    const int*   plen = (const int*)d_in[3];
    float* Og = (float*)d_out;

    char* ws = (char*)d_ws;
    unsigned short* Qb  = (unsigned short*)(ws);
    unsigned short* Kb  = (unsigned short*)(ws + (4u << 20));
    unsigned short* Vtb = (unsigned short*)(ws + (8u << 20));
    float* Op = (float*)(ws + (12u << 20));

    const size_t op_bytes = (size_t)NH * QL * DD * 4;   // 8 MB per split
    const size_t lp_bytes = (size_t)NH * QL * 4;        // 128 KB per split
    int nsplit = 1;
    if (ws_size >= (12u << 20) + 4 * (op_bytes + lp_bytes)) nsplit = 4;
    else if (ws_size >= (12u << 20) + 2 * (op_bytes + lp_bytes)) nsplit = 2;
    float* Lp = (float*)(ws + (12u << 20) + (size_t)nsplit * op_bytes);
    int spl = SL / nsplit;

    prep<<<dim3(2048, 3), 256, 0, stream>>>(Qf, Kf, Vf, Qb, Kb, Vtb);
    attn_mfma_reg<<<dim3(NH * (QL / 64), nsplit), 256, 0, stream>>>(Qb, Kb, Vtb, plen, Op, Lp, spl);
    combine<<<2048, 256, 0, stream>>>(Op, Lp, plen, Og, nsplit, spl);
}

// Round 6
// 111.800 us; speedup vs baseline: 1.7180x; 1.7180x over previous
//
#include <hip/hip_runtime.h>
#include <math.h>

#define NH 16
#define QL 2048
#define SL 2048
#define DD 64
#define PSTR 72
#define QK_SCALE_LOG2E 0.1803368801111f   // (8/64) * log2(e): fold softmax scale + ln2 into Q

typedef __attribute__((ext_vector_type(8))) short short8;
typedef __attribute__((ext_vector_type(4))) float floatx4;
typedef __attribute__((ext_vector_type(4))) unsigned short ushort4v;
typedef __attribute__((ext_vector_type(8))) unsigned short ushort8v;

__device__ __forceinline__ unsigned short f2bf(float x) {   // RNE fp32->bf16
    unsigned u = __float_as_uint(x);
    u += 0x7FFFu + ((u >> 16) & 1u);
    return (unsigned short)(u >> 16);
}

// async global->LDS, 16B per lane; LDS dest = wave-uniform base + lane*16
__device__ __forceinline__ void gld16(const unsigned short* g, unsigned short* l) {
    __builtin_amdgcn_global_load_lds(
        (const __attribute__((address_space(1))) unsigned int*)g,
        (__attribute__((address_space(3))) unsigned int*)l, 16, 0, 0);
}

// ---------------- prep: y=0 Q*(scale*log2e)->bf16, y=1 K->bf16, y=2 V->V^T bf16 ----------------
__global__ __launch_bounds__(256) void prep(
    const float* __restrict__ Qf, const float* __restrict__ Kf, const float* __restrict__ Vf,
    unsigned short* __restrict__ Qb, unsigned short* __restrict__ Kb, unsigned short* __restrict__ Vtb)
{
    if (blockIdx.y < 2) {
        int idx = blockIdx.x * 256 + threadIdx.x;          // float4 index, NH*QL*DD/4 = 524288
        const float4* src; unsigned short* dst; float scale;
        if (blockIdx.y == 0) { src = (const float4*)Qf; dst = Qb; scale = QK_SCALE_LOG2E; }
        else                 { src = (const float4*)Kf; dst = Kb; scale = 1.0f; }
        float4 v = src[idx];
        ushort4v h = { f2bf(v.x * scale), f2bf(v.y * scale), f2bf(v.z * scale), f2bf(v.w * scale) };
        *(ushort4v*)(dst + (size_t)idx * 4) = h;
    } else {
        if (blockIdx.x >= 512) return;                     // 16 heads x 32 s-tiles
        __shared__ unsigned short sT[64][PSTR];
        int bx = blockIdx.x;
        int n = bx >> 5, stile = bx & 31, s0 = stile * 64;
        int tid = (int)threadIdx.x;
        const float* vb = Vf + ((size_t)n * SL + s0) * DD;
        #pragma unroll
        for (int i = 0; i < 4; ++i) {
            int idx = tid + i * 256;
            int r = idx >> 4, c = (idx & 15) << 2;
            float4 v = *(const float4*)(vb + r * DD + c);
            sT[c + 0][r] = f2bf(v.x);
            sT[c + 1][r] = f2bf(v.y);
            sT[c + 2][r] = f2bf(v.z);
            sT[c + 3][r] = f2bf(v.w);
        }
        __syncthreads();
        int d = tid >> 2, sg = tid & 3;
        unsigned short* out = Vtb + (size_t)n * DD * SL + (size_t)d * SL + s0 + sg * 16;
        ushort8v a, b;
        #pragma unroll
        for (int i = 0; i < 8; ++i) { a[i] = sT[d][sg * 16 + i]; b[i] = sT[d][sg * 16 + 8 + i]; }
        *(ushort8v*)(out) = a;
        *(ushort8v*)(out + 8) = b;
    }
}

// ---------------- attention: split-S, fixed-max softmax, dbuf K/V staging, 40KB LDS ----------------
__global__ __launch_bounds__(256, 4) void attn_mfma_split(
    const unsigned short* __restrict__ Qb, const unsigned short* __restrict__ Kb,
    const unsigned short* __restrict__ Vtb, const int* __restrict__ plen_g,
    float* __restrict__ Op, float* __restrict__ Lp, int spl)
{
    // K/V: 64x64 bf16 tiles, row = 64 ushorts (128B, NO pad: global_load_lds needs lane*16 dest),
    // chunk c of row r at slot c ^ (r&7) (swizzle on the global fetch side).
    // sP: per-wave P[q][s], stride 64, ushort offset o stored at o ^ ((q&7)*8).
    __shared__ unsigned short sK[2][64 * 64];
    __shared__ unsigned short sVt[2][64 * 64];
    __shared__ unsigned short sP[4 * 16 * 64];

    const int blk = blockIdx.x;
    const int n  = blk & (NH - 1);
    const int qt = blk >> 4;
    const int q0 = qt * 64;
    const int sp = blockIdx.y;
    const int sbeg = sp * spl;
    const int plen = plen_g[n];
    const int ntile = spl >> 6;
    const bool hasdiag = (q0 >= sbeg) && (q0 < sbeg + spl);
    if (!((sbeg < plen) || hasdiag)) return;       // must match combine's predicate

    const int tid  = (int)threadIdx.x;
    const int wave = tid >> 6, lane = tid & 63, quad = lane >> 4, l16 = lane & 15;

    // active tiles: [0, base) prefix tiles + the diagonal tile if beyond base
    int rem  = plen - sbeg;
    int base = (rem > 0) ? min((rem + 63) >> 6, ntile) : 0;
    int td   = hasdiag ? ((q0 - sbeg) >> 6) : -1;
    int total = base + ((td >= base) ? 1 : 0);

    const int qrow  = wave * 16 + l16;             // local q row within block
    const int qglob = q0 + qrow;
    const int pmask = (l16 & 7) * 8;               // sP XOR swizzle (bits 3-5; b128-safe)

    // Q fragments register-direct from global (loop-invariant): B[n=q][k=ks*32+quad*8+j]
    const unsigned short* qg = Qb + ((size_t)(n * QL + qglob)) * DD + quad * 8;
    short8 bQ0 = *(const short8*)(qg);
    short8 bQ1 = *(const short8*)(qg + 32);

    const unsigned short* kh = Kb  + (size_t)n * SL * DD;
    const unsigned short* vh = Vtb + (size_t)n * DD * SL;

    // per-wave staging lane mapping (shared by all gld16 rounds)
    const int seg0 = wave * 2, seg1 = wave * 2 + 1;
    const int r0 = seg0 * 8 + (lane >> 3), r1 = seg1 * 8 + (lane >> 3);
    const int cg0 = ((lane & 7) ^ (r0 & 7)) * 8, cg1 = ((lane & 7) ^ (r1 & 7)) * 8;

    // ---- prologue: stage first K/V tile into buf 0 ----
    {
        int t0 = (0 < base) ? 0 : td;
        const unsigned short* kg = kh + (size_t)(sbeg + t0 * 64) * DD;
        const unsigned short* vg = vh + (sbeg + t0 * 64);
        gld16(kg + r0 * DD + cg0, sK[0] + seg0 * 512);
        gld16(kg + r1 * DD + cg1, sK[0] + seg1 * 512);
        gld16(vg + (size_t)r0 * SL + cg0, sVt[0] + seg0 * 512);
        gld16(vg + (size_t)r1 * SL + cg1, sVt[0] + seg1 * 512);
    }

    floatx4 acc[4];
    #pragma unroll
    for (int dt = 0; dt < 4; ++dt) acc[dt] = (floatx4){0.f, 0.f, 0.f, 0.f};
    float lsum = 0.f;                              // per-lane partial of l for q = qglob
    unsigned short* pw = sP + qrow * 64;

    for (int i = 0; i < total; ++i) {
        __syncthreads();                           // buf[i&1] staged; prior reads of buf[(i+1)&1] done

        // prefetch tile i+1 into the other buffer (in flight during this tile's compute)
        if (i + 1 < total) {
            int tn = (i + 1 < base) ? (i + 1) : td;
            const unsigned short* kg = kh + (size_t)(sbeg + tn * 64) * DD;
            const unsigned short* vg = vh + (sbeg + tn * 64);
            unsigned short* dk = sK[(i + 1) & 1];
            unsigned short* dv = sVt[(i + 1) & 1];
            gld16(kg + r0 * DD + cg0, dk + seg0 * 512);
            gld16(kg + r1 * DD + cg1, dk + seg1 * 512);
            gld16(vg + (size_t)r0 * SL + cg0, dv + seg0 * 512);
            gld16(vg + (size_t)r1 * SL + cg1, dv + seg1 * 512);
        }

        const unsigned short* sk = sK[i & 1];
        const unsigned short* sv = sVt[i & 1];
        const int t  = (i < base) ? i : td;
        const int s0 = sbeg + t * 64;

        // ---- S^T = K·Q^T : D[s=st2*16+quad*4+r][q=l16] ----
        floatx4 sf[4];
        #pragma unroll
        for (int st2 = 0; st2 < 4; ++st2) sf[st2] = (floatx4){0.f, 0.f, 0.f, 0.f};
        #pragma unroll
        for (int st2 = 0; st2 < 4; ++st2) {
            int krow = st2 * 16 + l16;
            short8 aK0 = *(const short8*)(sk + krow * 64 + (((0 * 4 + quad) ^ (krow & 7)) * 8));
            short8 aK1 = *(const short8*)(sk + krow * 64 + (((1 * 4 + quad) ^ (krow & 7)) * 8));
            sf[st2] = __builtin_amdgcn_mfma_f32_16x16x32_bf16(aK0, bQ0, sf[st2], 0, 0, 0);
            sf[st2] = __builtin_amdgcn_mfma_f32_16x16x32_bf16(aK1, bQ1, sf[st2], 0, 0, 0);
        }

        // ---- fixed-max softmax: p = exp2(prescaled score); no cross-lane ops ----
        if (s0 + 64 <= plen) {                     // fully-valid tile
            #pragma unroll
            for (int st2 = 0; st2 < 4; ++st2) {
                float p0 = __builtin_amdgcn_exp2f(sf[st2][0]);
                float p1 = __builtin_amdgcn_exp2f(sf[st2][1]);
                float p2 = __builtin_amdgcn_exp2f(sf[st2][2]);
                float p3 = __builtin_amdgcn_exp2f(sf[st2][3]);
                lsum += (p0 + p1) + (p2 + p3);
                ushort4v pk = { f2bf(p0), f2bf(p1), f2bf(p2), f2bf(p3) };
                *(ushort4v*)(pw + ((st2 * 16 + quad * 4) ^ pmask)) = pk;   // P^T-pack, swizzled
            }
        } else {
            #pragma unroll
            for (int st2 = 0; st2 < 4; ++st2) {
                float p[4];
                #pragma unroll
                for (int r = 0; r < 4; ++r) {
                    int s = s0 + st2 * 16 + quad * 4 + r;
                    bool valid = (s < plen) || (s == qglob);
                    p[r] = __builtin_amdgcn_exp2f(valid ? sf[st2][r] : -INFINITY);
                    lsum += p[r];
                }
                ushort4v pk = { f2bf(p[0]), f2bf(p[1]), f2bf(p[2]), f2bf(p[3]) };
                *(ushort4v*)(pw + ((st2 * 16 + quad * 4) ^ pmask)) = pk;
            }
        }

        // ---- PV: O[q][d] += P·V (A = P rows q, B = V^T rows d) ----
        #pragma unroll
        for (int ks = 0; ks < 2; ++ks) {
            short8 aP = *(const short8*)(pw + ((ks * 32 + quad * 8) ^ pmask));
            #pragma unroll
            for (int dt = 0; dt < 4; ++dt) {
                int vrow = dt * 16 + l16;
                short8 bV = *(const short8*)(sv + vrow * 64 + (((ks * 4 + quad) ^ (vrow & 7)) * 8));
                acc[dt] = __builtin_amdgcn_mfma_f32_16x16x32_bf16(aP, bV, acc[dt], 0, 0, 0);
            }
        }
    }

    // ---- epilogue: unnormalized partials ----
    lsum += __shfl_xor(lsum, 16, 64);
    lsum += __shfl_xor(lsum, 32, 64);
    if (quad == 0)
        Lp[((size_t)sp * NH + n) * QL + q0 + qrow] = lsum;

    float* ob = Op + (((size_t)sp * NH + n) * QL + q0) * DD;
    #pragma unroll
    for (int r = 0; r < 4; ++r) {
        int ql = wave * 16 + quad * 4 + r;
        #pragma unroll
        for (int dt = 0; dt < 4; ++dt)
            ob[(size_t)ql * DD + dt * 16 + l16] = acc[dt][r];
    }
}

// ---------------- combine: O = sum(Op) / sum(Lp) over contributing splits ----------------
__global__ __launch_bounds__(256) void combine(
    const float* __restrict__ Op, const float* __restrict__ Lp,
    const int* __restrict__ plen_g, float* __restrict__ Og, int nsplit, int spl)
{
    int idx = blockIdx.x * 256 + (int)threadIdx.x;    // float4 index, NH*QL*DD/4
    int d4 = idx & 15;
    int q  = (idx >> 4) & (QL - 1);
    int n  = idx >> 15;
    int plen = plen_g[n];
    int spd = q / spl;
    float4 s = {0.f, 0.f, 0.f, 0.f};
    float l = 0.f;
    for (int sp = 0; sp < nsplit; ++sp) {
        if ((sp * spl < plen) || (sp == spd)) {       // same predicate as attn early-exit
            const float* ob = Op + (((size_t)sp * NH + n) * QL + q) * DD;
            float4 v = *(const float4*)(ob + d4 * 4);
            s.x += v.x; s.y += v.y; s.z += v.z; s.w += v.w;
            l += Lp[((size_t)sp * NH + n) * QL + q];
        }
    }
    float inv = 1.0f / l;
    float4 o = { s.x * inv, s.y * inv, s.z * inv, s.w * inv };
    *(float4*)(Og + ((size_t)n * QL + q) * DD + d4 * 4) = o;
}

extern "C" void kernel_launch(void* const* d_in, const int* in_sizes, int n_in,
                              void* d_out, int out_size, void* d_ws, size_t ws_size,
                              hipStream_t stream) {
    const float* Qf   = (const float*)d_in[0];
    const float* Kf   = (const float*)d_in[1];
    const float* Vf   = (const float*)d_in[2];
    const int*   plen = (const int*)d_in[3];
    float* Og = (float*)d_out;

    char* ws = (char*)d_ws;
    unsigned short* Qb  = (unsigned short*)(ws);
    unsigned short* Kb  = (unsigned short*)(ws + (4u << 20));
    unsigned short* Vtb = (unsigned short*)(ws + (8u << 20));
    float* Op = (float*)(ws + (12u << 20));

    const size_t op_bytes = (size_t)NH * QL * DD * 4;   // 8 MB per split
    const size_t lp_bytes = (size_t)NH * QL * 4;        // 128 KB per split
    int nsplit = 1;
    if (ws_size >= (12u << 20) + 4 * (op_bytes + lp_bytes)) nsplit = 4;
    else if (ws_size >= (12u << 20) + 2 * (op_bytes + lp_bytes)) nsplit = 2;
    float* Lp = (float*)(ws + (12u << 20) + (size_t)nsplit * op_bytes);
    int spl = SL / nsplit;

    prep<<<dim3(2048, 3), 256, 0, stream>>>(Qf, Kf, Vf, Qb, Kb, Vtb);
    attn_mfma_split<<<dim3(NH * (QL / 64), nsplit), 256, 0, stream>>>(Qb, Kb, Vtb, plen, Op, Lp, spl);
    combine<<<2048, 256, 0, stream>>>(Op, Lp, plen, Og, nsplit, spl);
}

// Round 7
// 111.518 us; speedup vs baseline: 1.7223x; 1.0025x over previous
//
#include <hip/hip_runtime.h>
#include <hip/hip_bf16.h>
#include <math.h>

#define NH 16
#define QL 2048
#define SL 2048
#define DD 64
#define PSTR 72
#define QK_SCALE_LOG2E 0.1803368801111f   // (8/64) * log2(e): fold softmax scale + ln2 into Q

typedef __attribute__((ext_vector_type(8))) short short8;
typedef __attribute__((ext_vector_type(4))) float floatx4;
typedef __attribute__((ext_vector_type(4))) unsigned short ushort4v;
typedef __attribute__((ext_vector_type(8))) unsigned short ushort8v;

__device__ __forceinline__ unsigned short f2bf(float x) {   // RNE fp32->bf16
    unsigned u = __float_as_uint(x);
    u += 0x7FFFu + ((u >> 16) & 1u);
    return (unsigned short)(u >> 16);
}
__device__ __forceinline__ unsigned int f2bf2u(float x, float y) {  // packed pair (low=x)
    __hip_bfloat162 h = __float22bfloat162_rn(make_float2(x, y));
    return *(unsigned int*)&h;
}
__device__ __forceinline__ float bf2f(unsigned short h) {
    return __uint_as_float((unsigned)h << 16);
}

// async global->LDS, 16B per lane; LDS dest = wave-uniform base + lane*16
__device__ __forceinline__ void gld16(const unsigned short* g, unsigned short* l) {
    __builtin_amdgcn_global_load_lds(
        (const __attribute__((address_space(1))) unsigned int*)g,
        (__attribute__((address_space(3))) unsigned int*)l, 16, 0, 0);
}

// ---------------- prep: y=0 K->bf16, y=1 V->V^T bf16 ----------------
__global__ __launch_bounds__(256) void prep(
    const float* __restrict__ Kf, const float* __restrict__ Vf,
    unsigned short* __restrict__ Kb, unsigned short* __restrict__ Vtb)
{
    if (blockIdx.y == 0) {
        int idx = blockIdx.x * 256 + threadIdx.x;          // float4 index, NH*SL*DD/4 = 524288
        float4 v = ((const float4*)Kf)[idx];
        ushort4v h = { f2bf(v.x), f2bf(v.y), f2bf(v.z), f2bf(v.w) };
        *(ushort4v*)(Kb + (size_t)idx * 4) = h;
    } else {
        if (blockIdx.x >= 512) return;                     // 16 heads x 32 s-tiles
        __shared__ unsigned short sT[64][PSTR];
        int bx = blockIdx.x;
        int n = bx >> 5, stile = bx & 31, s0 = stile * 64;
        int tid = (int)threadIdx.x;
        const float* vb = Vf + ((size_t)n * SL + s0) * DD;
        #pragma unroll
        for (int i = 0; i < 4; ++i) {
            int idx = tid + i * 256;
            int r = idx >> 4, c = (idx & 15) << 2;
            float4 v = *(const float4*)(vb + r * DD + c);
            sT[c + 0][r] = f2bf(v.x);
            sT[c + 1][r] = f2bf(v.y);
            sT[c + 2][r] = f2bf(v.z);
            sT[c + 3][r] = f2bf(v.w);
        }
        __syncthreads();
        int d = tid >> 2, sg = tid & 3;
        unsigned short* out = Vtb + (size_t)n * DD * SL + (size_t)d * SL + s0 + sg * 16;
        ushort8v a, b;
        #pragma unroll
        for (int i = 0; i < 8; ++i) { a[i] = sT[d][sg * 16 + i]; b[i] = sT[d][sg * 16 + 8 + i]; }
        *(ushort8v*)(out) = a;
        *(ushort8v*)(out + 8) = b;
    }
}

// ---------------- attention: split-S, fixed-max softmax, dbuf K/V staging ----------------
__global__ __launch_bounds__(256, 4) void attn_mfma_split(
    const float* __restrict__ Qf, const unsigned short* __restrict__ Kb,
    const unsigned short* __restrict__ Vtb, const int* __restrict__ plen_g,
    unsigned short* __restrict__ Opb, float* __restrict__ Lp, int spl)
{
    // K/V: 64x64 bf16 tiles, row = 64 ushorts (128B, NO pad: global_load_lds needs lane*16 dest),
    // chunk c of row r at slot c ^ (r&7) (swizzle on the global fetch side).
    // sP: per-wave P[q][s], stride 64, ushort offset o stored at o ^ ((q&7)*8).
    __shared__ unsigned short sK[2][64 * 64];
    __shared__ unsigned short sVt[2][64 * 64];
    __shared__ unsigned short sP[4 * 16 * 64];

    const int blk = blockIdx.x;
    const int n  = blk & (NH - 1);
    const int qt = blk >> 4;
    const int q0 = qt * 64;
    const int sp = blockIdx.y;
    const int sbeg = sp * spl;
    const int plen = plen_g[n];
    const int ntile = spl >> 6;
    const bool hasdiag = (q0 >= sbeg) && (q0 < sbeg + spl);
    if (!((sbeg < plen) || hasdiag)) return;       // must match combine's predicate

    const int tid  = (int)threadIdx.x;
    const int wave = tid >> 6, lane = tid & 63, quad = lane >> 4, l16 = lane & 15;

    // active tiles: [0, base) prefix tiles + the diagonal tile if beyond base
    int rem  = plen - sbeg;
    int base = (rem > 0) ? min((rem + 63) >> 6, ntile) : 0;
    int td   = hasdiag ? ((q0 - sbeg) >> 6) : -1;
    int total = base + ((td >= base) ? 1 : 0);

    const int qrow  = wave * 16 + l16;             // local q row within block
    const int qglob = q0 + qrow;
    const int pmask = (l16 & 7) * 8;               // sP XOR swizzle (bits 3-5; b128-safe)

    // Q fragments: fp32 global -> bf16 regs once (loop-invariant), scale folded in
    short8 bQ0, bQ1;
    {
        const float* qf = Qf + ((size_t)(n * QL + qglob)) * DD + quad * 8;
        float4 a0 = *(const float4*)(qf);
        float4 a1 = *(const float4*)(qf + 4);
        float4 c0 = *(const float4*)(qf + 32);
        float4 c1 = *(const float4*)(qf + 36);
        const float S = QK_SCALE_LOG2E;
        unsigned int u0[4] = {
            f2bf2u(a0.x * S, a0.y * S), f2bf2u(a0.z * S, a0.w * S),
            f2bf2u(a1.x * S, a1.y * S), f2bf2u(a1.z * S, a1.w * S) };
        unsigned int u1[4] = {
            f2bf2u(c0.x * S, c0.y * S), f2bf2u(c0.z * S, c0.w * S),
            f2bf2u(c1.x * S, c1.y * S), f2bf2u(c1.z * S, c1.w * S) };
        bQ0 = *(short8*)u0;
        bQ1 = *(short8*)u1;
    }

    const unsigned short* kh = Kb  + (size_t)n * SL * DD;
    const unsigned short* vh = Vtb + (size_t)n * DD * SL;

    // per-wave staging lane mapping (shared by all gld16 rounds)
    const int seg0 = wave * 2, seg1 = wave * 2 + 1;
    const int r0 = seg0 * 8 + (lane >> 3), r1 = seg1 * 8 + (lane >> 3);
    const int cg0 = ((lane & 7) ^ (r0 & 7)) * 8, cg1 = ((lane & 7) ^ (r1 & 7)) * 8;

    // ---- prologue: stage first K/V tile into buf 0 ----
    {
        int t0 = (0 < base) ? 0 : td;
        const unsigned short* kg = kh + (size_t)(sbeg + t0 * 64) * DD;
        const unsigned short* vg = vh + (sbeg + t0 * 64);
        gld16(kg + r0 * DD + cg0, sK[0] + seg0 * 512);
        gld16(kg + r1 * DD + cg1, sK[0] + seg1 * 512);
        gld16(vg + (size_t)r0 * SL + cg0, sVt[0] + seg0 * 512);
        gld16(vg + (size_t)r1 * SL + cg1, sVt[0] + seg1 * 512);
    }

    floatx4 acc[4];
    #pragma unroll
    for (int dt = 0; dt < 4; ++dt) acc[dt] = (floatx4){0.f, 0.f, 0.f, 0.f};
    float lsum = 0.f;                              // per-lane partial of l for q = qglob
    unsigned short* pw = sP + qrow * 64;

    for (int i = 0; i < total; ++i) {
        __syncthreads();                           // buf[i&1] staged; prior reads of buf[(i+1)&1] done

        // prefetch tile i+1 into the other buffer (in flight during this tile's compute)
        if (i + 1 < total) {
            int tn = (i + 1 < base) ? (i + 1) : td;
            const unsigned short* kg = kh + (size_t)(sbeg + tn * 64) * DD;
            const unsigned short* vg = vh + (sbeg + tn * 64);
            unsigned short* dk = sK[(i + 1) & 1];
            unsigned short* dv = sVt[(i + 1) & 1];
            gld16(kg + r0 * DD + cg0, dk + seg0 * 512);
            gld16(kg + r1 * DD + cg1, dk + seg1 * 512);
            gld16(vg + (size_t)r0 * SL + cg0, dv + seg0 * 512);
            gld16(vg + (size_t)r1 * SL + cg1, dv + seg1 * 512);
        }

        const unsigned short* sk = sK[i & 1];
        const unsigned short* sv = sVt[i & 1];
        const int t  = (i < base) ? i : td;
        const int s0 = sbeg + t * 64;

        // ---- S^T = K·Q^T : D[s=st2*16+quad*4+r][q=l16] ----
        floatx4 sf[4];
        #pragma unroll
        for (int st2 = 0; st2 < 4; ++st2) sf[st2] = (floatx4){0.f, 0.f, 0.f, 0.f};
        #pragma unroll
        for (int st2 = 0; st2 < 4; ++st2) {
            int krow = st2 * 16 + l16;
            short8 aK0 = *(const short8*)(sk + krow * 64 + (((0 * 4 + quad) ^ (krow & 7)) * 8));
            short8 aK1 = *(const short8*)(sk + krow * 64 + (((1 * 4 + quad) ^ (krow & 7)) * 8));
            sf[st2] = __builtin_amdgcn_mfma_f32_16x16x32_bf16(aK0, bQ0, sf[st2], 0, 0, 0);
            sf[st2] = __builtin_amdgcn_mfma_f32_16x16x32_bf16(aK1, bQ1, sf[st2], 0, 0, 0);
        }

        // ---- fixed-max softmax: p = exp2(prescaled score); no cross-lane ops ----
        if (s0 + 64 <= plen) {                     // fully-valid tile
            #pragma unroll
            for (int st2 = 0; st2 < 4; ++st2) {
                float p0 = __builtin_amdgcn_exp2f(sf[st2][0]);
                float p1 = __builtin_amdgcn_exp2f(sf[st2][1]);
                float p2 = __builtin_amdgcn_exp2f(sf[st2][2]);
                float p3 = __builtin_amdgcn_exp2f(sf[st2][3]);
                lsum += (p0 + p1) + (p2 + p3);
                uint2 pk = { f2bf2u(p0, p1), f2bf2u(p2, p3) };
                *(uint2*)(pw + ((st2 * 16 + quad * 4) ^ pmask)) = pk;   // P^T-pack, swizzled
            }
        } else {
            #pragma unroll
            for (int st2 = 0; st2 < 4; ++st2) {
                float p[4];
                #pragma unroll
                for (int r = 0; r < 4; ++r) {
                    int s = s0 + st2 * 16 + quad * 4 + r;
                    bool valid = (s < plen) || (s == qglob);
                    p[r] = __builtin_amdgcn_exp2f(valid ? sf[st2][r] : -INFINITY);
                    lsum += p[r];
                }
                uint2 pk = { f2bf2u(p[0], p[1]), f2bf2u(p[2], p[3]) };
                *(uint2*)(pw + ((st2 * 16 + quad * 4) ^ pmask)) = pk;
            }
        }

        // ---- PV: O[q][d] += P·V (A = P rows q, B = V^T rows d) ----
        #pragma unroll
        for (int ks = 0; ks < 2; ++ks) {
            short8 aP = *(const short8*)(pw + ((ks * 32 + quad * 8) ^ pmask));
            #pragma unroll
            for (int dt = 0; dt < 4; ++dt) {
                int vrow = dt * 16 + l16;
                short8 bV = *(const short8*)(sv + vrow * 64 + (((ks * 4 + quad) ^ (vrow & 7)) * 8));
                acc[dt] = __builtin_amdgcn_mfma_f32_16x16x32_bf16(aP, bV, acc[dt], 0, 0, 0);
            }
        }
    }

    // ---- epilogue: unnormalized partials, bf16, coalesced via per-wave sP transpose ----
    lsum += __shfl_xor(lsum, 16, 64);
    lsum += __shfl_xor(lsum, 32, 64);
    if (quad == 0)
        Lp[((size_t)sp * NH + n) * QL + q0 + qrow] = lsum;

    // sP region is free for this wave (its last PV read already consumed it; wave-private)
    unsigned short* pws = sP + wave * 16 * 64;
    #pragma unroll
    for (int dt = 0; dt < 4; ++dt) {
        int chunk = dt * 2 + (l16 >> 3);           // 16B chunk 0..7 within row
        #pragma unroll
        for (int r = 0; r < 4; ++r) {
            int row = quad * 4 + r;
            int sw = ((chunk ^ (row & 7)) * 8) + (l16 & 7);
            pws[row * 64 + sw] = f2bf(acc[dt][r]);
        }
    }
    const size_t qbase = ((size_t)sp * NH + n) * QL + q0 + wave * 16;
    #pragma unroll
    for (int t = 0; t < 2; ++t) {
        int row = t * 8 + (lane >> 3);
        int chunk = lane & 7;
        int sw = (chunk ^ (row & 7)) * 8;
        ushort8v val = *(const ushort8v*)(pws + row * 64 + sw);
        *(ushort8v*)(Opb + (qbase + row) * DD + chunk * 8) = val;
    }
}

// ---------------- combine: O = sum(Opb) / sum(Lp) over contributing splits ----------------
__global__ __launch_bounds__(256) void combine(
    const unsigned short* __restrict__ Opb, const float* __restrict__ Lp,
    const int* __restrict__ plen_g, float* __restrict__ Og, int nsplit, int spl)
{
    int idx = blockIdx.x * 256 + (int)threadIdx.x;    // 4-elem group index, NH*QL*DD/4
    int d4 = idx & 15;
    int q  = (idx >> 4) & (QL - 1);
    int n  = idx >> 15;
    int plen = plen_g[n];
    int spd = q / spl;
    float4 s = {0.f, 0.f, 0.f, 0.f};
    float l = 0.f;
    for (int sp = 0; sp < nsplit; ++sp) {
        if ((sp * spl < plen) || (sp == spd)) {       // same predicate as attn early-exit
            const unsigned short* ob = Opb + (((size_t)sp * NH + n) * QL + q) * DD + d4 * 4;
            ushort4v v = *(const ushort4v*)(ob);
            s.x += bf2f(v[0]); s.y += bf2f(v[1]); s.z += bf2f(v[2]); s.w += bf2f(v[3]);
            l += Lp[((size_t)sp * NH + n) * QL + q];
        }
    }
    float inv = 1.0f / l;
    float4 o = { s.x * inv, s.y * inv, s.z * inv, s.w * inv };
    *(float4*)(Og + ((size_t)n * QL + q) * DD + d4 * 4) = o;
}

extern "C" void kernel_launch(void* const* d_in, const int* in_sizes, int n_in,
                              void* d_out, int out_size, void* d_ws, size_t ws_size,
                              hipStream_t stream) {
    const float* Qf   = (const float*)d_in[0];
    const float* Kf   = (const float*)d_in[1];
    const float* Vf   = (const float*)d_in[2];
    const int*   plen = (const int*)d_in[3];
    float* Og = (float*)d_out;

    char* ws = (char*)d_ws;
    unsigned short* Kb  = (unsigned short*)(ws);                 // 4 MB
    unsigned short* Vtb = (unsigned short*)(ws + (4u << 20));    // 4 MB
    unsigned short* Opb = (unsigned short*)(ws + (8u << 20));    // nsplit * 4 MB

    const size_t op_bytes = (size_t)NH * QL * DD * 2;   // 4 MB per split (bf16)
    const size_t lp_bytes = (size_t)NH * QL * 4;        // 128 KB per split
    int nsplit = 1;
    if (ws_size >= (8u << 20) + 4 * (op_bytes + lp_bytes)) nsplit = 4;
    else if (ws_size >= (8u << 20) + 2 * (op_bytes + lp_bytes)) nsplit = 2;
    float* Lp = (float*)(ws + (8u << 20) + (size_t)nsplit * op_bytes);
    int spl = SL / nsplit;

    prep<<<dim3(2048, 2), 256, 0, stream>>>(Kf, Vf, Kb, Vtb);
    attn_mfma_split<<<dim3(NH * (QL / 64), nsplit), 256, 0, stream>>>(Qf, Kb, Vtb, plen, Opb, Lp, spl);
    combine<<<2048, 256, 0, stream>>>(Opb, Lp, plen, Og, nsplit, spl);
}

// Round 8
// 109.550 us; speedup vs baseline: 1.7533x; 1.0180x over previous
//
#include <hip/hip_runtime.h>
#include <hip/hip_bf16.h>
#include <math.h>

#define NH 16
#define QL 2048
#define SL 2048
#define DD 64
#define BQ 128
#define PSTR 72
#define QK_SCALE_LOG2E 0.1803368801111f   // (8/64) * log2(e): fold softmax scale + ln2 into Q

typedef __attribute__((ext_vector_type(8))) short short8;
typedef __attribute__((ext_vector_type(4))) float floatx4;
typedef __attribute__((ext_vector_type(4))) unsigned short ushort4v;
typedef __attribute__((ext_vector_type(8))) unsigned short ushort8v;

__device__ __forceinline__ unsigned short f2bf(float x) {   // RNE fp32->bf16
    unsigned u = __float_as_uint(x);
    u += 0x7FFFu + ((u >> 16) & 1u);
    return (unsigned short)(u >> 16);
}
__device__ __forceinline__ unsigned int f2bf2u(float x, float y) {  // packed pair (low=x)
    __hip_bfloat162 h = __float22bfloat162_rn(make_float2(x, y));
    return *(unsigned int*)&h;
}
__device__ __forceinline__ float bf2f(unsigned short h) {
    return __uint_as_float((unsigned)h << 16);
}

// async global->LDS, 16B per lane; LDS dest = wave-uniform base + lane*16
__device__ __forceinline__ void gld16(const unsigned short* g, unsigned short* l) {
    __builtin_amdgcn_global_load_lds(
        (const __attribute__((address_space(1))) unsigned int*)g,
        (__attribute__((address_space(3))) unsigned int*)l, 16, 0, 0);
}

// ---------------- prep: y=0 K->bf16, y=1 V->V^T bf16 ----------------
__global__ __launch_bounds__(256) void prep(
    const float* __restrict__ Kf, const float* __restrict__ Vf,
    unsigned short* __restrict__ Kb, unsigned short* __restrict__ Vtb)
{
    if (blockIdx.y == 0) {
        int idx = blockIdx.x * 256 + threadIdx.x;          // float4 index, NH*SL*DD/4 = 524288
        float4 v = ((const float4*)Kf)[idx];
        ushort4v h = { f2bf(v.x), f2bf(v.y), f2bf(v.z), f2bf(v.w) };
        *(ushort4v*)(Kb + (size_t)idx * 4) = h;
    } else {
        if (blockIdx.x >= 512) return;                     // 16 heads x 32 s-tiles
        __shared__ unsigned short sT[64][PSTR];
        int bx = blockIdx.x;
        int n = bx >> 5, stile = bx & 31, s0 = stile * 64;
        int tid = (int)threadIdx.x;
        const float* vb = Vf + ((size_t)n * SL + s0) * DD;
        #pragma unroll
        for (int i = 0; i < 4; ++i) {
            int idx = tid + i * 256;
            int r = idx >> 4, c = (idx & 15) << 2;
            float4 v = *(const float4*)(vb + r * DD + c);
            sT[c + 0][r] = f2bf(v.x);
            sT[c + 1][r] = f2bf(v.y);
            sT[c + 2][r] = f2bf(v.z);
            sT[c + 3][r] = f2bf(v.w);
        }
        __syncthreads();
        int d = tid >> 2, sg = tid & 3;
        unsigned short* out = Vtb + (size_t)n * DD * SL + (size_t)d * SL + s0 + sg * 16;
        ushort8v a, b;
        #pragma unroll
        for (int i = 0; i < 8; ++i) { a[i] = sT[d][sg * 16 + i]; b[i] = sT[d][sg * 16 + 8 + i]; }
        *(ushort8v*)(out) = a;
        *(ushort8v*)(out + 8) = b;
    }
}

// ---------------- attention: BQ=128, 8 waves, split-S, fixed-max softmax, dbuf K/V ----------------
__global__ __launch_bounds__(512, 6) void attn_mfma_split(
    const float* __restrict__ Qf, const unsigned short* __restrict__ Kb,
    const unsigned short* __restrict__ Vtb, const int* __restrict__ plen_g,
    unsigned short* __restrict__ Opb, float* __restrict__ Lp, int spl)
{
    // K/V: 64x64 bf16 tiles, row = 64 ushorts (128B, NO pad: global_load_lds needs lane*16 dest),
    // chunk c of row r at slot c ^ (r&7) (swizzle on the global fetch side).
    // sP: per-wave P[q][s], stride 64, ushort offset o stored at o ^ ((l16&7)*8).
    __shared__ unsigned short sK[2][64 * 64];
    __shared__ unsigned short sVt[2][64 * 64];
    __shared__ unsigned short sP[8 * 16 * 64];

    const int blk = blockIdx.x;
    const int n  = blk & (NH - 1);
    const int qt = blk >> 4;
    const int q0 = qt * BQ;
    const int sp = blockIdx.y;
    const int sbeg = sp * spl;
    const int plen = plen_g[n];
    const int ntile = spl >> 6;
    // diag s-range [q0, q0+128) lies wholly in one split (q0-sbeg is a multiple of 128)
    const bool hasdiag = (q0 >= sbeg) && (q0 < sbeg + spl);
    if (!((sbeg < plen) || hasdiag)) return;       // must match combine's predicate

    const int tid  = (int)threadIdx.x;
    const int wave = tid >> 6, lane = tid & 63, quad = lane >> 4, l16 = lane & 15;

    // active tiles: [0, base) prefix tiles + diag tiles td0/td1 if beyond base
    int rem  = plen - sbeg;
    int base = (rem > 0) ? min((rem + 63) >> 6, ntile) : 0;
    int td0 = -1, td1 = -1;
    if (hasdiag) {
        int d0 = (q0 - sbeg) >> 6;
        if (d0 >= base) td0 = d0;
        if (d0 + 1 >= base) td1 = d0 + 1;
    }
    const int total = base + (td0 >= 0) + (td1 >= 0);

    const int qrow  = wave * 16 + l16;             // local q row within block (0..127)
    const int qglob = q0 + qrow;
    const int pmask = (l16 & 7) * 8;               // sP XOR swizzle (bits 3-5; b128-safe)

    // Q fragments: fp32 global -> bf16 regs once (loop-invariant), scale folded in
    short8 bQ0, bQ1;
    {
        const float* qf = Qf + ((size_t)(n * QL + qglob)) * DD + quad * 8;
        float4 a0 = *(const float4*)(qf);
        float4 a1 = *(const float4*)(qf + 4);
        float4 c0 = *(const float4*)(qf + 32);
        float4 c1 = *(const float4*)(qf + 36);
        const float S = QK_SCALE_LOG2E;
        unsigned int u0[4] = {
            f2bf2u(a0.x * S, a0.y * S), f2bf2u(a0.z * S, a0.w * S),
            f2bf2u(a1.x * S, a1.y * S), f2bf2u(a1.z * S, a1.w * S) };
        unsigned int u1[4] = {
            f2bf2u(c0.x * S, c0.y * S), f2bf2u(c0.z * S, c0.w * S),
            f2bf2u(c1.x * S, c1.y * S), f2bf2u(c1.z * S, c1.w * S) };
        bQ0 = *(short8*)u0;
        bQ1 = *(short8*)u1;
    }

    const unsigned short* kh = Kb  + (size_t)n * SL * DD;
    const unsigned short* vh = Vtb + (size_t)n * DD * SL;

    // staging lane mapping: each of 8 waves moves one 1KB segment of K and of V per tile
    const int rr = wave * 8 + (lane >> 3);
    const int cg = ((lane & 7) ^ (rr & 7)) * 8;

    auto tile_of = [&](int i) -> int {
        if (i < base) return i;
        if (i == base) return (td0 >= 0) ? td0 : td1;
        return td1;
    };

    // ---- prologue: stage first K/V tile into buf 0 ----
    {
        int t0 = tile_of(0);
        const unsigned short* kg = kh + (size_t)(sbeg + t0 * 64) * DD;
        const unsigned short* vg = vh + (sbeg + t0 * 64);
        gld16(kg + rr * DD + cg, sK[0] + wave * 512);
        gld16(vg + (size_t)rr * SL + cg, sVt[0] + wave * 512);
    }

    floatx4 acc[4];
    #pragma unroll
    for (int dt = 0; dt < 4; ++dt) acc[dt] = (floatx4){0.f, 0.f, 0.f, 0.f};
    float lsum = 0.f;                              // per-lane partial of l for q = qglob
    unsigned short* pw = sP + qrow * 64;

    for (int i = 0; i < total; ++i) {
        __syncthreads();                           // buf[i&1] staged; prior reads of buf[(i+1)&1] done

        // prefetch tile i+1 into the other buffer (in flight during this tile's compute)
        if (i + 1 < total) {
            int tn = tile_of(i + 1);
            const unsigned short* kg = kh + (size_t)(sbeg + tn * 64) * DD;
            const unsigned short* vg = vh + (sbeg + tn * 64);
            gld16(kg + rr * DD + cg, sK[(i + 1) & 1] + wave * 512);
            gld16(vg + (size_t)rr * SL + cg, sVt[(i + 1) & 1] + wave * 512);
        }

        const unsigned short* sk = sK[i & 1];
        const unsigned short* sv = sVt[i & 1];
        const int t  = tile_of(i);
        const int s0 = sbeg + t * 64;

        // ---- S^T = K·Q^T : D[s=st2*16+quad*4+r][q=l16] ----
        floatx4 sf[4];
        #pragma unroll
        for (int st2 = 0; st2 < 4; ++st2) sf[st2] = (floatx4){0.f, 0.f, 0.f, 0.f};
        #pragma unroll
        for (int st2 = 0; st2 < 4; ++st2) {
            int krow = st2 * 16 + l16;
            short8 aK0 = *(const short8*)(sk + krow * 64 + (((0 * 4 + quad) ^ (krow & 7)) * 8));
            short8 aK1 = *(const short8*)(sk + krow * 64 + (((1 * 4 + quad) ^ (krow & 7)) * 8));
            sf[st2] = __builtin_amdgcn_mfma_f32_16x16x32_bf16(aK0, bQ0, sf[st2], 0, 0, 0);
            sf[st2] = __builtin_amdgcn_mfma_f32_16x16x32_bf16(aK1, bQ1, sf[st2], 0, 0, 0);
        }

        // ---- fixed-max softmax: p = exp2(prescaled score); no cross-lane ops ----
        if (s0 + 64 <= plen) {                     // fully-valid tile
            #pragma unroll
            for (int st2 = 0; st2 < 4; ++st2) {
                float p0 = __builtin_amdgcn_exp2f(sf[st2][0]);
                float p1 = __builtin_amdgcn_exp2f(sf[st2][1]);
                float p2 = __builtin_amdgcn_exp2f(sf[st2][2]);
                float p3 = __builtin_amdgcn_exp2f(sf[st2][3]);
                lsum += (p0 + p1) + (p2 + p3);
                uint2 pk = { f2bf2u(p0, p1), f2bf2u(p2, p3) };
                *(uint2*)(pw + ((st2 * 16 + quad * 4) ^ pmask)) = pk;   // P^T-pack, swizzled
            }
        } else {
            #pragma unroll
            for (int st2 = 0; st2 < 4; ++st2) {
                float p[4];
                #pragma unroll
                for (int r = 0; r < 4; ++r) {
                    int s = s0 + st2 * 16 + quad * 4 + r;
                    bool valid = (s < plen) || (s == qglob);
                    p[r] = __builtin_amdgcn_exp2f(valid ? sf[st2][r] : -INFINITY);
                    lsum += p[r];
                }
                uint2 pk = { f2bf2u(p[0], p[1]), f2bf2u(p[2], p[3]) };
                *(uint2*)(pw + ((st2 * 16 + quad * 4) ^ pmask)) = pk;
            }
        }

        // ---- PV: O[q][d] += P·V (A = P rows q, B = V^T rows d) ----
        #pragma unroll
        for (int ks = 0; ks < 2; ++ks) {
            short8 aP = *(const short8*)(pw + ((ks * 32 + quad * 8) ^ pmask));
            #pragma unroll
            for (int dt = 0; dt < 4; ++dt) {
                int vrow = dt * 16 + l16;
                short8 bV = *(const short8*)(sv + vrow * 64 + (((ks * 4 + quad) ^ (vrow & 7)) * 8));
                acc[dt] = __builtin_amdgcn_mfma_f32_16x16x32_bf16(aP, bV, acc[dt], 0, 0, 0);
            }
        }
    }

    // ---- epilogue: unnormalized partials, bf16, coalesced via per-wave sP transpose ----
    lsum += __shfl_xor(lsum, 16, 64);
    lsum += __shfl_xor(lsum, 32, 64);
    if (quad == 0)
        Lp[((size_t)sp * NH + n) * QL + q0 + qrow] = lsum;

    // sP region is free for this wave (its last PV read already consumed it; wave-private)
    unsigned short* pws = sP + wave * 16 * 64;
    #pragma unroll
    for (int dt = 0; dt < 4; ++dt) {
        int chunk = dt * 2 + (l16 >> 3);           // 16B chunk 0..7 within row
        #pragma unroll
        for (int r = 0; r < 4; ++r) {
            int row = quad * 4 + r;
            int sw = ((chunk ^ (row & 7)) * 8) + (l16 & 7);
            pws[row * 64 + sw] = f2bf(acc[dt][r]);
        }
    }
    const size_t qbase = ((size_t)sp * NH + n) * QL + q0 + wave * 16;
    #pragma unroll
    for (int t = 0; t < 2; ++t) {
        int row = t * 8 + (lane >> 3);
        int chunk = lane & 7;
        int sw = (chunk ^ (row & 7)) * 8;
        ushort8v val = *(const ushort8v*)(pws + row * 64 + sw);
        *(ushort8v*)(Opb + (qbase + row) * DD + chunk * 8) = val;
    }
}

// ---------------- combine: O = sum(Opb) / sum(Lp) over contributing splits ----------------
__global__ __launch_bounds__(256) void combine(
    const unsigned short* __restrict__ Opb, const float* __restrict__ Lp,
    const int* __restrict__ plen_g, float* __restrict__ Og, int nsplit, int spl)
{
    int idx = blockIdx.x * 256 + (int)threadIdx.x;    // 4-elem group index, NH*QL*DD/4
    int d4 = idx & 15;
    int q  = (idx >> 4) & (QL - 1);
    int n  = idx >> 15;
    int plen = plen_g[n];
    int spd = q / spl;
    float4 s = {0.f, 0.f, 0.f, 0.f};
    float l = 0.f;
    for (int sp = 0; sp < nsplit; ++sp) {
        if ((sp * spl < plen) || (sp == spd)) {       // same predicate as attn early-exit
            const unsigned short* ob = Opb + (((size_t)sp * NH + n) * QL + q) * DD + d4 * 4;
            ushort4v v = *(const ushort4v*)(ob);
            s.x += bf2f(v[0]); s.y += bf2f(v[1]); s.z += bf2f(v[2]); s.w += bf2f(v[3]);
            l += Lp[((size_t)sp * NH + n) * QL + q];
        }
    }
    float inv = 1.0f / l;
    float4 o = { s.x * inv, s.y * inv, s.z * inv, s.w * inv };
    *(float4*)(Og + ((size_t)n * QL + q) * DD + d4 * 4) = o;
}

extern "C" void kernel_launch(void* const* d_in, const int* in_sizes, int n_in,
                              void* d_out, int out_size, void* d_ws, size_t ws_size,
                              hipStream_t stream) {
    const float* Qf   = (const float*)d_in[0];
    const float* Kf   = (const float*)d_in[1];
    const float* Vf   = (const float*)d_in[2];
    const int*   plen = (const int*)d_in[3];
    float* Og = (float*)d_out;

    char* ws = (char*)d_ws;
    unsigned short* Kb  = (unsigned short*)(ws);                 // 4 MB
    unsigned short* Vtb = (unsigned short*)(ws + (4u << 20));    // 4 MB
    unsigned short* Opb = (unsigned short*)(ws + (8u << 20));    // nsplit * 4 MB

    const size_t op_bytes = (size_t)NH * QL * DD * 2;   // 4 MB per split (bf16)
    const size_t lp_bytes = (size_t)NH * QL * 4;        // 128 KB per split
    int nsplit = 1;
    if (ws_size >= (8u << 20) + 4 * (op_bytes + lp_bytes)) nsplit = 4;
    else if (ws_size >= (8u << 20) + 2 * (op_bytes + lp_bytes)) nsplit = 2;
    float* Lp = (float*)(ws + (8u << 20) + (size_t)nsplit * op_bytes);
    int spl = SL / nsplit;

    prep<<<dim3(2048, 2), 256, 0, stream>>>(Kf, Vf, Kb, Vtb);
    attn_mfma_split<<<dim3(NH * (QL / BQ), nsplit), 512, 0, stream>>>(Qf, Kb, Vtb, plen, Opb, Lp, spl);
    combine<<<2048, 256, 0, stream>>>(Opb, Lp, plen, Og, nsplit, spl);
}